// Round 7
// baseline (93.066 us; speedup 1.0000x reference)
//
#include <hip/hip_runtime.h>

#define NH 8
#define DCM 64
#define NB 2
#define NS 512
#define NL 384
#define LN_EPS 1e-5f
#define INV_SQRT_C 0.35355339059327379f

typedef __attribute__((ext_vector_type(8))) short short8v;   // 8 bf16 (4 VGPRs)
typedef __attribute__((ext_vector_type(4))) float f32x4;

__device__ __forceinline__ float4 ld4(const float* p) {
  return *reinterpret_cast<const float4*>(p);
}
__device__ __forceinline__ unsigned short f2bf(float f) {
  unsigned int b = __float_as_uint(f);
  b += 0x7FFFu + ((b >> 16) & 1u);          // round-to-nearest-even
  return (unsigned short)(b >> 16);
}
__device__ __forceinline__ float bf2f(unsigned short u) {
  return __uint_as_float(((unsigned int)u) << 16);
}

// ---------------------------------------------------------------------------
// Prep (one-time):
//   wt[0..4095]=wg^T bf16 [n][k]; wt[4096..8191]=wo^T; wt[8192..12287]=wv^T
//   Mg[j*512 + h*64 + cm] = sum_c wq[j][h*8+c]*wk[cm][h*8+c] / sqrt(C)  (f32)
// qk = (masked_sum_x @ Mg) / denom  — folds q_input->q->qk into one GEMV.
// ---------------------------------------------------------------------------
__global__ void prep(const float* __restrict__ wg, const float* __restrict__ wo,
                     const float* __restrict__ wv, const float* __restrict__ wq,
                     const float* __restrict__ wk,
                     unsigned short* __restrict__ wt, float* __restrict__ Mg) {
  int i = blockIdx.x * 256 + threadIdx.x;
  if (i < 4096) {
    int n = i >> 6, k = i & 63;
    wt[i]        = f2bf(wg[k * DCM + n]);
    wt[4096 + i] = f2bf(wo[k * DCM + n]);
    wt[8192 + i] = f2bf(wv[k * DCM + n]);
  }
  if (i < 32768) {
    int j = i >> 9, idx = i & 511, h = idx >> 6, cm = idx & 63;
    float a = 0.f;
#pragma unroll
    for (int c = 0; c < 8; ++c) a += wq[j * DCM + h * 8 + c] * wk[cm * DCM + h * 8 + c];
    Mg[i] = a * INV_SQRT_C;
  }
}

// ---------------------------------------------------------------------------
// Fused, 256 threads (4 waves), one WG per (b,l) column. m read ONCE.
//   P1   : shuffle-free LN — each lane owns 2 whole rows in registers
//   P2pre: masked sum of x from LDS (light; 2 shuffles at end) + mask denom
//   qkGEMV: qk = (qsum @ Mg)/denom  (Mg precomputed, L2-resident)
//   P2   : merged logits MFMA -> p (P_T, same wave) ; V MFMA ; og += p*V
//   P3   : gating MFMA -> IN-PLACE transpose into dead x_lds tile -> out MFMA
// LDS 78336 B -> 2 WGs/CU. __launch_bounds__(256,4): arg2 empirically =
// blocks/CU (R5/R6 measured) -> 4*4=16 waves/CU -> 128-VGPR cap.
// ---------------------------------------------------------------------------
__global__ __launch_bounds__(256, 4) void fused(
    const float* __restrict__ m, const float* __restrict__ msk,
    const float* __restrict__ lnw, const float* __restrict__ lnb,
    const unsigned short* __restrict__ wt, const float* __restrict__ Mg,
    const float* __restrict__ bg, const float* __restrict__ bo,
    float* __restrict__ out)
{
  const int col = blockIdx.x;              // b*NL + l
  const int b = col / NL, l = col % NL;
  const int tid = threadIdx.x;
  const int wave = tid >> 6, lane = tid & 63;   // wave 0..3

  __shared__ __align__(16) unsigned short x_lds[NS * DCM];   // 64 KB, swizzled
  __shared__ __align__(16) unsigned short mask_s[NS];        // 1 KB (0/1 exact)
  __shared__ __align__(16) unsigned char scratch[9728];      // overlays below
  __shared__ __align__(16) unsigned short qk_bf[16 * DCM];   // 2 KB, rows 8-15 = 0

  float* redf  = (float*)scratch;                   // [4][64] @ 0   (pre-qk)
  float* dredf = (float*)(scratch + 1024);          // [4]
  unsigned short* P_T = (unsigned short*)scratch;   // [8][512] bf16 @0 (P2; redf dead)
  float* ogredf = (float*)(scratch + 8192);         // [4][64]
  float* smredf = (float*)(scratch + 9216);         // [4][8]
  float* ogsf   = (float*)(scratch + 9344);         // [64]

  for (int i = tid; i < NS; i += 256)
    mask_s[i] = f2bf(msk[(b * NS + i) * NL + l]);

  // ---------------- Phase 1: shuffle-free LN, 2 whole rows per lane --------
#pragma unroll 1
  for (int rr = 0; rr < 2; ++rr) {
    const int r = tid + rr * 256;
    const float* rp = m + ((size_t)(b * NS + r) * NL + l) * DCM;
    float4 f[16];
#pragma unroll
    for (int j = 0; j < 16; ++j) f[j] = ld4(rp + j * 4);
    float s1 = 0.f, s2 = 0.f;
#pragma unroll
    for (int j = 0; j < 16; ++j) {
      s1 += (f[j].x + f[j].y) + (f[j].z + f[j].w);
      s2 = fmaf(f[j].x, f[j].x, s2); s2 = fmaf(f[j].y, f[j].y, s2);
      s2 = fmaf(f[j].z, f[j].z, s2); s2 = fmaf(f[j].w, f[j].w, s2);
    }
    const float mu = s1 * 0.015625f;
    const float rs = rsqrtf(s2 * 0.015625f - mu * mu + LN_EPS);
    const int swz = (r & 7) << 3;
#pragma unroll
    for (int j = 0; j < 8; ++j) {
      const float v[8] = {f[2*j].x, f[2*j].y, f[2*j].z, f[2*j].w,
                          f[2*j+1].x, f[2*j+1].y, f[2*j+1].z, f[2*j+1].w};
      short8v xp;
#pragma unroll
      for (int k = 0; k < 8; ++k)
        xp[k] = (short)f2bf((v[k] - mu) * rs * lnw[8*j+k] + lnb[8*j+k]);
      *reinterpret_cast<short8v*>(&x_lds[r * DCM + ((j * 8) ^ swz)]) = xp;
    }
  }
  __syncthreads();                  // x_lds + mask_s ready

  // ---------------- P2pre: masked sum of x + mask denom --------------------
  const int qd = lane & 15, rsub = lane >> 4;
  {
    float q0 = 0.f, q1 = 0.f, q2 = 0.f, q3 = 0.f, da = 0.f;
    for (int it = 0; it < 32; ++it) {
      const int s = wave * 4 + rsub + it * 16;
      short4 xv4 = *reinterpret_cast<const short4*>(
          &x_lds[s * DCM + ((qd * 4) ^ ((s & 7) << 3))]);
      const float mk = bf2f(mask_s[s]);
      q0 = fmaf(mk, bf2f((unsigned short)xv4.x), q0);
      q1 = fmaf(mk, bf2f((unsigned short)xv4.y), q1);
      q2 = fmaf(mk, bf2f((unsigned short)xv4.z), q2);
      q3 = fmaf(mk, bf2f((unsigned short)xv4.w), q3);
      da += mk;
    }
    q0 += __shfl_xor(q0, 16); q0 += __shfl_xor(q0, 32);
    q1 += __shfl_xor(q1, 16); q1 += __shfl_xor(q1, 32);
    q2 += __shfl_xor(q2, 16); q2 += __shfl_xor(q2, 32);
    q3 += __shfl_xor(q3, 16); q3 += __shfl_xor(q3, 32);
    da += __shfl_xor(da, 16); da += __shfl_xor(da, 32);
    if (lane < 16) {
      float4 t; t.x = q0; t.y = q1; t.z = q2; t.w = q3;
      *reinterpret_cast<float4*>(&redf[wave * DCM + qd * 4]) = t;
    }
    if (lane == 0) dredf[wave] = da;   // each row counted exactly once
    qk_bf[512 + tid] = 0;              // fake heads 8..15 = zero logits
    qk_bf[768 + tid] = 0;
  }
  __syncthreads();

  // ---------------- qk GEMV via precomputed Mg -----------------------------
  {
    const float inv_dn = 1.0f / fmaxf((dredf[0] + dredf[1]) + (dredf[2] + dredf[3]), 1.0f);
    float a0 = 0.f, a1 = 0.f;
    for (int j = 0; j < 64; ++j) {
      const float qs = (redf[j] + redf[64 + j]) + (redf[128 + j] + redf[192 + j]);
      a0 = fmaf(qs, Mg[j * 512 + tid], a0);
      a1 = fmaf(qs, Mg[j * 512 + tid + 256], a1);
    }
    qk_bf[tid]       = f2bf(a0 * inv_dn);
    qk_bf[tid + 256] = f2bf(a1 * inv_dn);
  }
  __syncthreads();   // qk ready; redf dead -> scratch becomes P_T

  // ---------------- Phase 2 (merged): logits+p, V, og += p*V ---------------
  const int bcol = lane & 15;
  const int kg = lane >> 4;
  const int rowbase = wave * 128;
  short8v qkB0 = *reinterpret_cast<const short8v*>(&qk_bf[bcol * DCM + kg * 8]);
  short8v qkB1 = *reinterpret_cast<const short8v*>(&qk_bf[bcol * DCM + 32 + kg * 8]);
  short8v wvB[4][2];
#pragma unroll
  for (int nt = 0; nt < 4; ++nt)
#pragma unroll
    for (int kw = 0; kw < 2; ++kw)
      wvB[nt][kw] = *reinterpret_cast<const short8v*>(
          &wt[8192 + (nt * 16 + bcol) * DCM + kw * 32 + kg * 8]);
  float smacc = 0.f;
  float ogacc[4] = {0.f, 0.f, 0.f, 0.f};
  for (int t = 0; t < 8; ++t) {
    const int tilebase = rowbase + t * 16;
    const int arow = tilebase + bcol;
    const int swz = (arow & 7) << 3;
    short8v a0 = *reinterpret_cast<const short8v*>(&x_lds[arow * DCM + ((kg * 8) ^ swz)]);
    short8v a1 = *reinterpret_cast<const short8v*>(&x_lds[arow * DCM + ((32 + kg * 8) ^ swz)]);
    f32x4 L = (f32x4){0.f, 0.f, 0.f, 0.f};
    L = __builtin_amdgcn_mfma_f32_16x16x32_bf16(a0, qkB0, L, 0, 0, 0);
    L = __builtin_amdgcn_mfma_f32_16x16x32_bf16(a1, qkB1, L, 0, 0, 0);
    const int s0 = tilebase + kg * 4;                // C rows = kg*4+r
    short4 mk4 = *reinterpret_cast<const short4*>(&mask_s[s0]);
    // logits are tiny (global query is a mean) -> exp without max-sub safe
    float p0 = bf2f((unsigned short)mk4.x) * __expf(L[0]);
    float p1 = bf2f((unsigned short)mk4.y) * __expf(L[1]);
    float p2 = bf2f((unsigned short)mk4.z) * __expf(L[2]);
    float p3 = bf2f((unsigned short)mk4.w) * __expf(L[3]);
    smacc += (p0 + p1) + (p2 + p3);
    if (bcol < NH) {                                 // producer lanes
      short4 pw;
      pw.x = (short)f2bf(p0); pw.y = (short)f2bf(p1);
      pw.z = (short)f2bf(p2); pw.w = (short)f2bf(p3);
      *reinterpret_cast<short4*>(&P_T[bcol * NS + (s0 ^ (bcol << 3))]) = pw;
    }
    f32x4 V[4];
#pragma unroll
    for (int nt = 0; nt < 4; ++nt) {
      V[nt] = (f32x4){0.f, 0.f, 0.f, 0.f};
      V[nt] = __builtin_amdgcn_mfma_f32_16x16x32_bf16(a0, wvB[nt][0], V[nt], 0, 0, 0);
      V[nt] = __builtin_amdgcn_mfma_f32_16x16x32_bf16(a1, wvB[nt][1], V[nt], 0, 0, 0);
    }
    // consume p (stored above by this same wave; in-wave LDS ops are ordered)
#pragma unroll
    for (int nt = 0; nt < 4; ++nt) {
      const int h2 = 2 * nt + (bcol >> 3);           // head of this lane's col
      short4 p4 = *reinterpret_cast<const short4*>(&P_T[h2 * NS + (s0 ^ (h2 << 3))]);
      ogacc[nt] += bf2f((unsigned short)p4.x) * V[nt][0]
                 + bf2f((unsigned short)p4.y) * V[nt][1]
                 + bf2f((unsigned short)p4.z) * V[nt][2]
                 + bf2f((unsigned short)p4.w) * V[nt][3];
    }
  }
  smacc += __shfl_xor(smacc, 16); smacc += __shfl_xor(smacc, 32);
  if (lane < NH) smredf[wave * NH + lane] = smacc;
#pragma unroll
  for (int nt = 0; nt < 4; ++nt) {
    ogacc[nt] += __shfl_xor(ogacc[nt], 16);
    ogacc[nt] += __shfl_xor(ogacc[nt], 32);
  }
  if (lane < 16) {
#pragma unroll
    for (int nt = 0; nt < 4; ++nt) ogredf[wave * DCM + nt * 16 + lane] = ogacc[nt];
  }
  __syncthreads();
  if (tid < DCM) {
    float smT = 0.f, a = 0.f;
#pragma unroll
    for (int w = 0; w < 4; ++w) {
      smT += smredf[w * NH + (tid >> 3)];
      a += ogredf[w * DCM + tid];
    }
    ogsf[tid] = a / fmaxf(smT, 1e-30f);
  }
  __syncthreads();   // og ready

  // ---------------- Phase 3: gating MFMA -> in-place transpose -> out ------
  short8v wgB[4][2], woB[4][2];
  float bgv[4], bov[4], ogv[4];
#pragma unroll
  for (int nt = 0; nt < 4; ++nt) {
    const int ncol = nt * 16 + bcol;
#pragma unroll
    for (int kw = 0; kw < 2; ++kw) {
      wgB[nt][kw] = *reinterpret_cast<const short8v*>(&wt[ncol * DCM + kw * 32 + kg * 8]);
      woB[nt][kw] = *reinterpret_cast<const short8v*>(&wt[4096 + ncol * DCM + kw * 32 + kg * 8]);
    }
    bgv[nt] = bg[ncol]; bov[nt] = bo[ncol]; ogv[nt] = ogsf[ncol];
  }
  const size_t outbase = ((size_t)b * NS * NL + l) * DCM;

  for (int t = 0; t < 8; ++t) {
    const int tilebase = rowbase + t * 16;
    const int arow = tilebase + bcol;
    const int swz = (arow & 7) << 3;
    short8v a0 = *reinterpret_cast<const short8v*>(&x_lds[arow * DCM + ((kg * 8) ^ swz)]);
    short8v a1 = *reinterpret_cast<const short8v*>(&x_lds[arow * DCM + ((32 + kg * 8) ^ swz)]);
    f32x4 accG[4];
#pragma unroll
    for (int nt = 0; nt < 4; ++nt) {
      accG[nt] = (f32x4){0.f, 0.f, 0.f, 0.f};
      accG[nt] = __builtin_amdgcn_mfma_f32_16x16x32_bf16(a0, wgB[nt][0], accG[nt], 0, 0, 0);
      accG[nt] = __builtin_amdgcn_mfma_f32_16x16x32_bf16(a1, wgB[nt][1], accG[nt], 0, 0, 0);
    }
    // gate*og, transposed bf16 written IN-PLACE into this (now dead) x tile.
    // In-wave LDS ordering: a0/a1 reads complete before these writes; each
    // wave owns its 128 rows exclusively.
#pragma unroll
    for (int nt = 0; nt < 4; ++nt) {
      const int cc = nt * 16 + bcol;
#pragma unroll
      for (int r = 0; r < 4; ++r) {
        const int r2 = kg * 4 + r;                 // C-layout row within tile
        float gx = accG[nt][r] + bgv[nt];
        float g = 1.0f / (1.0f + __expf(-gx));
        x_lds[(tilebase + r2) * DCM + (cc ^ ((r2 & 7) << 3))] = f2bf(g * ogv[nt]);
      }
    }
    short8v b0 = *reinterpret_cast<const short8v*>(
        &x_lds[(tilebase + bcol) * DCM + ((kg * 8) ^ ((bcol & 7) << 3))]);
    short8v b1 = *reinterpret_cast<const short8v*>(
        &x_lds[(tilebase + bcol) * DCM + ((32 + kg * 8) ^ ((bcol & 7) << 3))]);
    f32x4 accO[4];
#pragma unroll
    for (int nt = 0; nt < 4; ++nt) {
      accO[nt] = (f32x4){0.f, 0.f, 0.f, 0.f};
      accO[nt] = __builtin_amdgcn_mfma_f32_16x16x32_bf16(b0, woB[nt][0], accO[nt], 0, 0, 0);
      accO[nt] = __builtin_amdgcn_mfma_f32_16x16x32_bf16(b1, woB[nt][1], accO[nt], 0, 0, 0);
    }
#pragma unroll
    for (int nt = 0; nt < 4; ++nt) {
#pragma unroll
      for (int r = 0; r < 4; ++r) {
        const int orow = tilebase + kg * 4 + r;
        const float mk = bf2f(mask_s[orow]);
        out[outbase + (size_t)orow * NL * DCM + nt * 16 + bcol] = (accO[nt][r] + bov[nt]) * mk;
      }
    }
  }
}

extern "C" void kernel_launch(void* const* d_in, const int* in_sizes, int n_in,
                              void* d_out, int out_size, void* d_ws, size_t ws_size,
                              hipStream_t stream) {
  (void)in_sizes; (void)n_in; (void)out_size; (void)ws_size;
  const float* m   = (const float*)d_in[0];
  const float* msk = (const float*)d_in[1];
  const float* lnw = (const float*)d_in[2];
  const float* lnb = (const float*)d_in[3];
  const float* wq  = (const float*)d_in[4];
  const float* wk  = (const float*)d_in[5];
  const float* wv  = (const float*)d_in[6];
  const float* wg  = (const float*)d_in[7];
  const float* bg  = (const float*)d_in[8];
  const float* wo  = (const float*)d_in[9];
  const float* bo  = (const float*)d_in[10];
  unsigned short* wt = (unsigned short*)d_ws;              // 24576 B
  float* Mg = (float*)((char*)d_ws + 24576);               // 131072 B (ws>=196KB proven R1)
  float* out = (float*)d_out;

  prep<<<dim3(128), dim3(256), 0, stream>>>(wg, wo, wv, wq, wk, wt, Mg);
  fused<<<dim3(NB * NL), dim3(256), 0, stream>>>(
      m, msk, lnw, lnb, wt, Mg, bg, bo, out);
}